// Round 1
// baseline (320.225 us; speedup 1.0000x reference)
//
#include <hip/hip_runtime.h>

// YOLO layer: (64, 30, 152, 152) fp32 -> (64, 3*152*152, 10) fp32
// Memory-bound transpose + elementwise (sigmoid/exp). Roofline ~56us @6.3TB/s.

constexpr int G    = 152;
constexpr int G2   = G * G;      // 23104
constexpr int NA   = 3;
constexpr int NOUT = 10;         // NUM_CLASSES + 7
constexpr int P4   = G2 / 4;     // 5776 float4-groups per (b,a) plane

__device__ __forceinline__ float fast_sigmoid(float v) {
    return 1.0f / (1.0f + __expf(-v));
}

__global__ __launch_bounds__(256) void yolo_kernel(
    const float* __restrict__ x,
    const int*   __restrict__ img_size_p,
    float*       __restrict__ out,
    int total4)
{
    int idx = blockIdx.x * 256 + threadIdx.x;
    if (idx >= total4) return;

    // img_size is a 1-element array; per harness rules it's int32, but hedge
    // against a float32 materialization via bit-pattern plausibility.
    int iv = *img_size_p;
    float img_size;
    if (iv > 0 && iv < (1 << 20)) {
        img_size = (float)iv;
    } else {
        img_size = __int_as_float(iv);
    }
    const float stride = img_size / (float)G;   // 8.0

    const float aw[NA] = {12.0f, 19.0f, 40.0f};
    const float ah[NA] = {16.0f, 36.0f, 28.0f};

    int pos4 = idx % P4;
    int ba   = idx / P4;         // b*3 + a
    int a    = ba % NA;

    int pos = pos4 * 4;          // linear position within the (g,g) plane
    int y   = pos / G;           // G%4==0 -> all 4 positions share a row
    int x0  = pos - y * G;

    // 10 coalesced float4 channel loads: x[(ba*10+ch)*G2 + pos .. +3]
    float4 p[NOUT];
    const float* xbase = x + (size_t)ba * (NOUT * G2) + pos;
#pragma unroll
    for (int ch = 0; ch < NOUT; ++ch)
        p[ch] = *reinterpret_cast<const float4*>(xbase + (size_t)ch * G2);

    // boxes are scaled by stride at the end; anchor_w = (A/stride), so the
    // net factor is (A/stride)*stride (kept literal to match the reference).
    const float anchor_w = (aw[a] / stride) * stride;
    const float anchor_h = (ah[a] / stride) * stride;

    alignas(16) float buf[4 * NOUT];
#pragma unroll
    for (int j = 0; j < 4; ++j) {
        const float v0 = reinterpret_cast<const float*>(&p[0])[j];
        const float v1 = reinterpret_cast<const float*>(&p[1])[j];
        const float v2 = reinterpret_cast<const float*>(&p[2])[j];
        const float v3 = reinterpret_cast<const float*>(&p[3])[j];
        const float v4 = reinterpret_cast<const float*>(&p[4])[j];
        const float v5 = reinterpret_cast<const float*>(&p[5])[j];
        const float v6 = reinterpret_cast<const float*>(&p[6])[j];
        const float v7 = reinterpret_cast<const float*>(&p[7])[j];
        const float v8 = reinterpret_cast<const float*>(&p[8])[j];
        const float v9 = reinterpret_cast<const float*>(&p[9])[j];

        const float bx = fast_sigmoid(v0) * 1.05f - 0.5f * (1.05f - 1.0f);
        const float by = fast_sigmoid(v1) * 1.05f - 0.5f * (1.05f - 1.0f);

        buf[j * NOUT + 0] = (bx + (float)(x0 + j)) * stride;
        buf[j * NOUT + 1] = (by + (float)y) * stride;
        buf[j * NOUT + 2] = __expf(v2) * anchor_w;
        buf[j * NOUT + 3] = __expf(v3) * anchor_h;
        buf[j * NOUT + 4] = v4;
        buf[j * NOUT + 5] = v5;
        buf[j * NOUT + 6] = fast_sigmoid(v6);
        buf[j * NOUT + 7] = fast_sigmoid(v7);
        buf[j * NOUT + 8] = fast_sigmoid(v8);
        buf[j * NOUT + 9] = fast_sigmoid(v9);
    }

    // 160B contiguous, 16B-aligned store per thread: 10x float4
    float4* op = reinterpret_cast<float4*>(out + (size_t)(ba * G2 + pos) * NOUT);
#pragma unroll
    for (int k = 0; k < NOUT; ++k)
        op[k] = reinterpret_cast<const float4*>(buf)[k];
}

extern "C" void kernel_launch(void* const* d_in, const int* in_sizes, int n_in,
                              void* d_out, int out_size, void* d_ws, size_t ws_size,
                              hipStream_t stream) {
    const float* x = (const float*)d_in[0];
    const int* img_size_p = (const int*)d_in[1];
    float* out = (float*)d_out;

    const int total4 = 64 * NA * P4;          // 1,108,992 threads
    const int blocks = (total4 + 255) / 256;  // 4332
    yolo_kernel<<<blocks, 256, 0, stream>>>(x, img_size_p, out, total4);
}

// Round 2
// 304.865 us; speedup vs baseline: 1.0504x; 1.0504x over previous
//
#include <hip/hip_runtime.h>

// YOLO layer: (64, 30, 152, 152) fp32 -> (64, 3*152*152, 10) fp32
// Memory-bound transpose + elementwise. Roofline ~44-56us for ~274-355MB @6.3TB/s.
// R1 lesson: direct strided stores (160B lane stride) cap at 2.3TB/s (29% peak)
// due to partial-line L2 write transactions. R2: stage output in LDS, write
// fully coalesced (lane stride 16B).

constexpr int G    = 152;
constexpr int G2   = G * G;      // 23104
constexpr int NA   = 3;
constexpr int NOUT = 10;         // NUM_CLASSES + 7
constexpr int P4   = G2 / 4;     // 5776 float4-groups per (b,a) plane

typedef float floatx4 __attribute__((ext_vector_type(4)));

__device__ __forceinline__ float fast_sigmoid(float v) {
    return 1.0f / (1.0f + __expf(-v));
}

// grid = 4332 blocks x 256 threads; each thread owns 4 consecutive positions
// (gp = global position in the linear (b,a,pos) space of 4,435,968 positions;
// 4332*1024 tiles it exactly -> no bounds guard, safe with __syncthreads).
__global__ __launch_bounds__(256) void yolo_kernel(
    const float* __restrict__ x,
    const int*   __restrict__ img_size_p,
    float*       __restrict__ out)
{
    __shared__ float lds[256 * 4 * NOUT];   // 40 KB: 1024 positions x 10 ch

    const int t   = threadIdx.x;
    const int idx = blockIdx.x * 256 + t;   // float4-group id

    // img_size: 1-element array, int32 per harness rules; hedge for fp32 bits.
    int iv = *img_size_p;
    float img_size = (iv > 0 && iv < (1 << 20)) ? (float)iv : __int_as_float(iv);
    const float stride = img_size / (float)G;   // 8.0

    const float aw[NA] = {12.0f, 19.0f, 40.0f};
    const float ah[NA] = {16.0f, 36.0f, 28.0f};

    const int pos4 = idx % P4;
    const int ba   = idx / P4;       // b*3 + a
    const int a    = ba % NA;

    const int pos = pos4 * 4;        // G%4==0 -> 4 positions share a grid row
    const int y   = pos / G;
    const int x0  = pos - y * G;

    // 10 coalesced float4 channel loads
    float4 p[NOUT];
    const float* xbase = x + (size_t)ba * (NOUT * G2) + pos;
#pragma unroll
    for (int ch = 0; ch < NOUT; ++ch)
        p[ch] = *reinterpret_cast<const float4*>(xbase + (size_t)ch * G2);

    const float anchor_w = (aw[a] / stride) * stride;
    const float anchor_h = (ah[a] / stride) * stride;

    alignas(16) float buf[4 * NOUT];
#pragma unroll
    for (int j = 0; j < 4; ++j) {
        const float v0 = reinterpret_cast<const float*>(&p[0])[j];
        const float v1 = reinterpret_cast<const float*>(&p[1])[j];
        const float v2 = reinterpret_cast<const float*>(&p[2])[j];
        const float v3 = reinterpret_cast<const float*>(&p[3])[j];
        const float v4 = reinterpret_cast<const float*>(&p[4])[j];
        const float v5 = reinterpret_cast<const float*>(&p[5])[j];
        const float v6 = reinterpret_cast<const float*>(&p[6])[j];
        const float v7 = reinterpret_cast<const float*>(&p[7])[j];
        const float v8 = reinterpret_cast<const float*>(&p[8])[j];
        const float v9 = reinterpret_cast<const float*>(&p[9])[j];

        const float bx = fast_sigmoid(v0) * 1.05f - 0.5f * (1.05f - 1.0f);
        const float by = fast_sigmoid(v1) * 1.05f - 0.5f * (1.05f - 1.0f);

        buf[j * NOUT + 0] = (bx + (float)(x0 + j)) * stride;
        buf[j * NOUT + 1] = (by + (float)y) * stride;
        buf[j * NOUT + 2] = __expf(v2) * anchor_w;
        buf[j * NOUT + 3] = __expf(v3) * anchor_h;
        buf[j * NOUT + 4] = v4;
        buf[j * NOUT + 5] = v5;
        buf[j * NOUT + 6] = fast_sigmoid(v6);
        buf[j * NOUT + 7] = fast_sigmoid(v7);
        buf[j * NOUT + 8] = fast_sigmoid(v8);
        buf[j * NOUT + 9] = fast_sigmoid(v9);
    }

    // Stage to LDS: thread t owns float4-slots [t*10, t*10+10).
    // Start-bank stride 8*t%32 -> ~4-way aliasing; LDS cost is ~30x under the
    // HBM floor for this block, so no padding/swizzle needed.
    floatx4* l4 = reinterpret_cast<floatx4*>(lds);
    const floatx4* b4 = reinterpret_cast<const floatx4*>(buf);
#pragma unroll
    for (int w = 0; w < NOUT; ++w)
        l4[t * NOUT + w] = b4[w];

    __syncthreads();

    // Coalesced writeback: 10 rounds, lane i writes 16B at lane-stride 16B.
    // Nontemporal: output is write-once; keep L2/L3 warm for the input.
    floatx4* dst = reinterpret_cast<floatx4*>(out) + (size_t)blockIdx.x * (256 * NOUT);
#pragma unroll
    for (int r = 0; r < NOUT; ++r) {
        floatx4 v = l4[r * 256 + t];
        __builtin_nontemporal_store(v, dst + r * 256 + t);
    }
}

extern "C" void kernel_launch(void* const* d_in, const int* in_sizes, int n_in,
                              void* d_out, int out_size, void* d_ws, size_t ws_size,
                              hipStream_t stream) {
    const float* x = (const float*)d_in[0];
    const int* img_size_p = (const int*)d_in[1];
    float* out = (float*)d_out;

    const int total4 = 64 * NA * P4;          // 1,108,992 thread-groups
    const int blocks = total4 / 256;          // 4332, exact
    yolo_kernel<<<blocks, 256, 0, stream>>>(x, img_size_p, out);
}

// Round 3
// 300.390 us; speedup vs baseline: 1.0660x; 1.0149x over previous
//
#include <hip/hip_runtime.h>

// YOLO layer: (64, 30, 152, 152) fp32 -> (64, 3*152*152, 10) fp32
// Memory-bound transpose + elementwise. Traffic floor ~264-355MB -> 42-56us @6.3TB/s.
// R1: direct 160B-stride stores -> 2.3TB/s (29% peak), 117us.
// R2: LDS-staged coalesced writeback, 40KB LDS -> ~100us; LDS caps occupancy at
//     4 blocks/CU (50%) and staging writes had partial bank conflicts.
// R3: 2 positions/thread -> 20KB LDS -> 8 blocks/CU (100% occupancy);
//     20-dword staging stride -> conflict-free b128 LDS writes.

constexpr int G    = 152;
constexpr int G2   = G * G;      // 23104
constexpr int NA   = 3;
constexpr int NOUT = 10;         // NUM_CLASSES + 7
constexpr int P2   = G2 / 2;     // 11552 float2-groups per (b,a) plane

typedef float floatx4 __attribute__((ext_vector_type(4)));

__device__ __forceinline__ float fast_sigmoid(float v) {
    return 1.0f / (1.0f + __expf(-v));
}

// grid = 8664 blocks x 256 threads; each thread owns 2 consecutive positions.
// 8664*256 tiles the 2,217,984 float2-groups exactly -> no bounds guard.
__global__ __launch_bounds__(256) void yolo_kernel(
    const float* __restrict__ x,
    const int*   __restrict__ img_size_p,
    float*       __restrict__ out)
{
    __shared__ float lds[256 * 2 * NOUT];   // 20 KB: 512 positions x 10 ch

    const int t   = threadIdx.x;
    const int idx = blockIdx.x * 256 + t;   // float2-group id

    // img_size: 1-element array, int32 per harness rules; hedge for fp32 bits.
    int iv = *img_size_p;
    float img_size = (iv > 0 && iv < (1 << 20)) ? (float)iv : __int_as_float(iv);
    const float stride = img_size / (float)G;   // 8.0

    const float aw[NA] = {12.0f, 19.0f, 40.0f};
    const float ah[NA] = {16.0f, 36.0f, 28.0f};

    const int pos2 = idx % P2;
    const int ba   = idx / P2;       // b*3 + a
    const int a    = ba % NA;

    const int pos = pos2 * 2;        // G%2==0 -> both positions share a grid row
    const int y   = pos / G;
    const int x0  = pos - y * G;

    // 10 coalesced float2 channel loads (lane stride 8B -> 512B/wave/instr)
    float2 p[NOUT];
    const float* xbase = x + (size_t)ba * (NOUT * G2) + pos;
#pragma unroll
    for (int ch = 0; ch < NOUT; ++ch)
        p[ch] = *reinterpret_cast<const float2*>(xbase + (size_t)ch * G2);

    const float anchor_w = (aw[a] / stride) * stride;
    const float anchor_h = (ah[a] / stride) * stride;

    alignas(16) float buf[2 * NOUT];
#pragma unroll
    for (int j = 0; j < 2; ++j) {
        const float v0 = j ? p[0].y : p[0].x;
        const float v1 = j ? p[1].y : p[1].x;
        const float v2 = j ? p[2].y : p[2].x;
        const float v3 = j ? p[3].y : p[3].x;
        const float v4 = j ? p[4].y : p[4].x;
        const float v5 = j ? p[5].y : p[5].x;
        const float v6 = j ? p[6].y : p[6].x;
        const float v7 = j ? p[7].y : p[7].x;
        const float v8 = j ? p[8].y : p[8].x;
        const float v9 = j ? p[9].y : p[9].x;

        const float bx = fast_sigmoid(v0) * 1.05f - 0.5f * (1.05f - 1.0f);
        const float by = fast_sigmoid(v1) * 1.05f - 0.5f * (1.05f - 1.0f);

        buf[j * NOUT + 0] = (bx + (float)(x0 + j)) * stride;
        buf[j * NOUT + 1] = (by + (float)y) * stride;
        buf[j * NOUT + 2] = __expf(v2) * anchor_w;
        buf[j * NOUT + 3] = __expf(v3) * anchor_h;
        buf[j * NOUT + 4] = v4;
        buf[j * NOUT + 5] = v5;
        buf[j * NOUT + 6] = fast_sigmoid(v6);
        buf[j * NOUT + 7] = fast_sigmoid(v7);
        buf[j * NOUT + 8] = fast_sigmoid(v8);
        buf[j * NOUT + 9] = fast_sigmoid(v9);
    }

    // Stage to LDS: thread t owns float4-slots [t*5, t*5+5).
    // Start banks (20t)%32 over 8-lane service groups cover all 32 banks ->
    // conflict-free ds_write_b128.
    floatx4* l4 = reinterpret_cast<floatx4*>(lds);
    const floatx4* b4 = reinterpret_cast<const floatx4*>(buf);
#pragma unroll
    for (int w = 0; w < 5; ++w)
        l4[t * 5 + w] = b4[w];

    __syncthreads();

    // Coalesced writeback: 5 rounds, lane i writes 16B at lane-stride 16B.
    // Nontemporal: output is write-once; keep L2/L3 warm for the input.
    floatx4* dst = reinterpret_cast<floatx4*>(out) + (size_t)blockIdx.x * (256 * 5);
#pragma unroll
    for (int r = 0; r < 5; ++r) {
        floatx4 v = l4[r * 256 + t];
        __builtin_nontemporal_store(v, dst + r * 256 + t);
    }
}

extern "C" void kernel_launch(void* const* d_in, const int* in_sizes, int n_in,
                              void* d_out, int out_size, void* d_ws, size_t ws_size,
                              hipStream_t stream) {
    const float* x = (const float*)d_in[0];
    const int* img_size_p = (const int*)d_in[1];
    float* out = (float*)d_out;

    const int total2 = 64 * NA * P2;          // 2,217,984 thread-groups
    const int blocks = total2 / 256;          // 8664, exact
    yolo_kernel<<<blocks, 256, 0, stream>>>(x, img_size_p, out);
}